// Round 1
// baseline (304.175 us; speedup 1.0000x reference)
//
#include <hip/hip_runtime.h>

#define CV_B 8
#define CV_C 128
#define CV_H 128
#define CV_W 240
#define CV_V 48
#define LSTRIDE 136   // bf16 elems per c-row in LDS: 128 + 8 pad (keeps 16B align, spreads banks)

typedef __attribute__((ext_vector_type(8))) short bf16x8;
typedef __attribute__((ext_vector_type(4))) float f32x4;

// RTNE pack of two fp32 -> packed bf16x2 (inputs are finite gaussians; NaN path not needed)
__device__ __forceinline__ unsigned int pack2_bf16(float f0, float f1) {
    unsigned int u0 = __float_as_uint(f0);
    unsigned int u1 = __float_as_uint(f1);
    u0 += 0x7fffu + ((u0 >> 16) & 1u);
    u1 += 0x7fffu + ((u1 >> 16) & 1u);
    return (u0 >> 16) | (u1 & 0xffff0000u);
}

__global__ __launch_bounds__(256, 4) void cost_volume_kernel(
        const float* __restrict__ Lf, const float* __restrict__ Rf,
        float* __restrict__ out)
{
    __shared__ __align__(16) short sL[16 * LSTRIDE];        // 4.25 KB
    __shared__ __align__(16) short sR[64 * LSTRIDE];        // 17 KB
    __shared__ float band[CV_V * 17];                       // 3.2 KB, stride 17 breaks conflicts

    const int t   = threadIdx.x;
    const int xt  = blockIdx.x * 16;          // x-tile base, 0..224
    const int y   = blockIdx.y;
    const int b   = blockIdx.z;
    const int jt0 = xt - 48;                  // leftmost right-image column needed

    const int plane = CV_H * CV_W;            // 30720 floats per (b,c) image row-block
    const float* Lbase = Lf + ((b * CV_C) * plane) + y * CV_W;
    const float* Rbase = Rf + ((b * CV_C) * plane) + y * CV_W;

    // ---- stage L tile: 16 x  x 128 c  (8 vals/thread -> 1 ds_write_b128) ----
    {
        const int xl = t & 15;
        const int c0 = (t >> 4) * 8;          // 0,8,...,120
        const float* p = Lbase + c0 * plane + (xt + xl);
        float v[8];
#pragma unroll
        for (int jj = 0; jj < 8; ++jj) v[jj] = p[jj * plane];
        uint4 w;
        w.x = pack2_bf16(v[0], v[1]);
        w.y = pack2_bf16(v[2], v[3]);
        w.z = pack2_bf16(v[4], v[5]);
        w.w = pack2_bf16(v[6], v[7]);
        *(uint4*)&sL[xl * LSTRIDE + c0] = w;
    }

    // ---- stage R tile: 64 j x 128 c, zero-pad j<0  (32 vals/thread -> 4 b128 writes) ----
    {
        const int jl = t & 63;
        const int cb = (t >> 6) * 32;         // 0,32,64,96
        const int jg = jt0 + jl;              // global j; max = xt+15 <= 239, may be < 0
        const bool ok = (jg >= 0);
        const float* p = Rbase + cb * plane + jg;
#pragma unroll
        for (int g = 0; g < 4; ++g) {
            float v[8];
#pragma unroll
            for (int jj = 0; jj < 8; ++jj)
                v[jj] = ok ? p[(g * 8 + jj) * plane] : 0.0f;
            uint4 w;
            w.x = pack2_bf16(v[0], v[1]);
            w.y = pack2_bf16(v[2], v[3]);
            w.z = pack2_bf16(v[4], v[5]);
            w.w = pack2_bf16(v[6], v[7]);
            *(uint4*)&sR[jl * LSTRIDE + cb + g * 8] = w;
        }
    }

    __syncthreads();

    // ---- MFMA: wave wv computes 16x16 tile  C[x, j] , j-tile = wv ----
    const int lane = t & 63;
    const int wv   = t >> 6;                  // 0..3: j-tile index
    const int n    = lane & 15;
    const int quad = lane >> 4;

    f32x4 acc = {0.f, 0.f, 0.f, 0.f};
#pragma unroll
    for (int ks = 0; ks < 4; ++ks) {
        const int k0 = ks * 32 + quad * 8;
        bf16x8 a  = *(const bf16x8*)&sL[n * LSTRIDE + k0];                 // A[m=n][k]
        bf16x8 bb = *(const bf16x8*)&sR[(wv * 16 + n) * LSTRIDE + k0];     // B[k][n]
        acc = __builtin_amdgcn_mfma_f32_16x16x32_bf16(a, bb, acc, 0, 0, 0);
    }

    // ---- scatter C (col=lane&15 -> j, row=quad*4+reg -> x) into band[i][x] ----
    const int jg = jt0 + wv * 16 + n;
#pragma unroll
    for (int r = 0; r < 4; ++r) {
        const int xl = quad * 4 + r;
        const int i  = (xt + xl) - jg;        // disparity
        if (i >= 0 && i < CV_V) band[i * 17 + xl] = acc[r] * (1.0f / 128.0f);
    }
    __syncthreads();

    // ---- coalesced store: 48 i-rows x 16 consecutive x (64B segments) ----
#pragma unroll
    for (int u = 0; u < 3; ++u) {
        const int idx = t + u * 256;
        const int i   = idx >> 4;
        const int xl  = idx & 15;
        out[((b * CV_V + i) * CV_H + y) * CV_W + xt + xl] = band[i * 17 + xl];
    }
}

extern "C" void kernel_launch(void* const* d_in, const int* in_sizes, int n_in,
                              void* d_out, int out_size, void* d_ws, size_t ws_size,
                              hipStream_t stream)
{
    const float* Lf = (const float*)d_in[0];
    const float* Rf = (const float*)d_in[1];
    float* o = (float*)d_out;
    dim3 grid(CV_W / 16, CV_H, CV_B);   // 15 x 128 x 8 = 15360 blocks
    dim3 block(256);
    hipLaunchKernelGGL(cost_volume_kernel, grid, block, 0, stream, Lf, Rf, o);
}

// Round 2
// 294.647 us; speedup vs baseline: 1.0323x; 1.0323x over previous
//
#include <hip/hip_runtime.h>

#define CV_B 8
#define CV_C 128
#define CV_H 128
#define CV_W 240
#define CV_V 48
#define NT   15        // x-tiles of 16 per row
#define LSTRIDE 136    // bf16 elems per LDS row: 128 + 8 pad (16B-aligned rows)
#define NSLOT 5        // R ring slots: window spans 4 tiles + 1 prefetch

typedef __attribute__((ext_vector_type(8))) short bf16x8;
typedef __attribute__((ext_vector_type(4))) float f32x4;

// RTNE pack of two fp32 -> packed bf16x2
__device__ __forceinline__ unsigned int pack2_bf16(float f0, float f1) {
    unsigned int u0 = __float_as_uint(f0);
    unsigned int u1 = __float_as_uint(f1);
    u0 += 0x7fffu + ((u0 >> 16) & 1u);
    u1 += 0x7fffu + ((u1 >> 16) & 1u);
    return (u0 >> 16) | (u1 & 0xffff0000u);
}

__global__ __launch_bounds__(256, 4) void cost_volume_kernel(
        const float* __restrict__ Lf, const float* __restrict__ Rf,
        float* __restrict__ out)
{
    // ring-buffered LDS: every input element enters LDS exactly once per block
    __shared__ __align__(16) short sL[2][16 * LSTRIDE];      //  8.5 KB (double buf)
    __shared__ __align__(16) short sR[NSLOT][16 * LSTRIDE];  // 21.3 KB (5-slot ring)
    __shared__ float band[CV_V * 17];                        //  3.3 KB

    const int t = threadIdx.x;
    const int y = blockIdx.x;
    const int b = blockIdx.y;

    const int plane = CV_H * CV_W;
    const float* Lrow = Lf + (b * CV_C) * plane + y * CV_W;
    const float* Rrow = Rf + (b * CV_C) * plane + y * CV_W;

    const int xl = t & 15;          // column within tile
    const int c0 = (t >> 4) * 8;    // channel group base: 0,8,...,120

    // ---- prologue: zero ring slots 2,3,4 (j-tiles -3,-2,-1 -> exact 0 outputs) ----
    {
        uint4 z = {0u, 0u, 0u, 0u};
        short* base = &sR[2][0];
        const int n128 = (3 * 16 * LSTRIDE) / 8;   // 816 b128 chunks
        for (int idx = t; idx < n128; idx += 256)
            *(uint4*)&base[idx * 8] = z;
    }
    // ---- prologue: stage L tile 0 -> buf 0, R j-tile 0 -> slot 0 ----
    {
        const float* pL = Lrow + c0 * plane + xl;
        const float* pR = Rrow + c0 * plane + xl;
        float lv[8], rv[8];
#pragma unroll
        for (int jj = 0; jj < 8; ++jj) { lv[jj] = pL[jj * plane]; rv[jj] = pR[jj * plane]; }
        uint4 wl, wr;
        wl.x = pack2_bf16(lv[0], lv[1]); wl.y = pack2_bf16(lv[2], lv[3]);
        wl.z = pack2_bf16(lv[4], lv[5]); wl.w = pack2_bf16(lv[6], lv[7]);
        wr.x = pack2_bf16(rv[0], rv[1]); wr.y = pack2_bf16(rv[2], rv[3]);
        wr.z = pack2_bf16(rv[4], rv[5]); wr.w = pack2_bf16(rv[6], rv[7]);
        *(uint4*)&sL[0][xl * LSTRIDE + c0] = wl;
        *(uint4*)&sR[0][xl * LSTRIDE + c0] = wr;
    }
    __syncthreads();

    const int lane = t & 63;
    const int wv   = t >> 6;        // wave -> j-tile offset (u = tt-3+wv)
    const int n    = lane & 15;
    const int quad = lane >> 4;

    for (int tt = 0; tt < NT; ++tt) {
        // 1) prefetch next 16 columns of L and R into registers (overlaps MFMA)
        float lv[8], rv[8];
        const bool pf = (tt + 1 < NT);
        if (pf) {
            const int xg = 16 * (tt + 1);
            const float* pL = Lrow + c0 * plane + xg + xl;
            const float* pR = Rrow + c0 * plane + xg + xl;
#pragma unroll
            for (int jj = 0; jj < 8; ++jj) { lv[jj] = pL[jj * plane]; rv[jj] = pR[jj * plane]; }
        }

        // 2) MFMA: wave wv computes j-tile u = tt-3+wv vs x-tile tt, K=128
        const int u    = tt - 3 + wv;
        const int slot = (u + NSLOT) % NSLOT;     // u >= -3, so u+5 >= 2
        const short* aRow = &sL[tt & 1][n * LSTRIDE];
        const short* bRow = &sR[slot][n * LSTRIDE];
        f32x4 acc = {0.f, 0.f, 0.f, 0.f};
#pragma unroll
        for (int ks = 0; ks < 4; ++ks) {
            const int k0 = ks * 32 + quad * 8;
            bf16x8 a  = *(const bf16x8*)&aRow[k0];
            bf16x8 bb = *(const bf16x8*)&bRow[k0];
            acc = __builtin_amdgcn_mfma_f32_16x16x32_bf16(a, bb, acc, 0, 0, 0);
        }

        // 3) scatter C (col=n -> j, row=quad*4+r -> x) into band; i is lane-static
#pragma unroll
        for (int r = 0; r < 4; ++r) {
            const int xloc = quad * 4 + r;
            const int i    = 16 * (3 - wv) + xloc - n;   // disparity, independent of tt
            if (i >= 0 && i < CV_V) band[i * 17 + xloc] = acc[r] * (1.0f / 128.0f);
        }
        __syncthreads();   // band complete; all tile-tt LDS reads done

        // 4) coalesced store: 48 i-rows x 16 x (64B per row-segment)
        const int xbase = 16 * tt;
#pragma unroll
        for (int uu = 0; uu < 3; ++uu) {
            const int idx = t + uu * 256;
            const int i   = idx >> 4;
            const int xx  = idx & 15;
            out[((b * CV_V + i) * CV_H + y) * CV_W + xbase + xx] = band[i * 17 + xx];
        }

        // 5) commit prefetch to LDS (slot (tt+1)%5 held tile tt-4: reads done at tt-1)
        if (pf) {
            uint4 wl, wr;
            wl.x = pack2_bf16(lv[0], lv[1]); wl.y = pack2_bf16(lv[2], lv[3]);
            wl.z = pack2_bf16(lv[4], lv[5]); wl.w = pack2_bf16(lv[6], lv[7]);
            wr.x = pack2_bf16(rv[0], rv[1]); wr.y = pack2_bf16(rv[2], rv[3]);
            wr.z = pack2_bf16(rv[4], rv[5]); wr.w = pack2_bf16(rv[6], rv[7]);
            *(uint4*)&sL[(tt + 1) & 1][xl * LSTRIDE + c0] = wl;
            *(uint4*)&sR[(tt + 1) % NSLOT][xl * LSTRIDE + c0] = wr;
        }
        __syncthreads();   // prefetched tiles visible; band free for next iter
    }
}

extern "C" void kernel_launch(void* const* d_in, const int* in_sizes, int n_in,
                              void* d_out, int out_size, void* d_ws, size_t ws_size,
                              hipStream_t stream)
{
    const float* Lf = (const float*)d_in[0];
    const float* Rf = (const float*)d_in[1];
    float* o = (float*)d_out;
    dim3 grid(CV_H, CV_B);   // one block per (y, b) row: 1024 blocks
    dim3 block(256);
    hipLaunchKernelGGL(cost_volume_kernel, grid, block, 0, stream, Lf, Rf, o);
}